// Round 2
// baseline (631.309 us; speedup 1.0000x reference)
//
#include <hip/hip_runtime.h>
#include <hip/hip_bf16.h>

// B=16, N=1024, R=10, De=64, Dr=32, H=64, cat_in=960
// out[b,m,h] = relu( bias[h] + sum_r sum_n adj[b,r,m,n] * Yt[br,h,n] )
// Yt[br,h,n] = sum_d x[b,n,d]*W[h, r*96+d] + c[br,h]
// c[br,h]    = sum_d rel[br,d]*W[h, r*96+64+d]

typedef __bf16 bf16x8 __attribute__((ext_vector_type(8)));
typedef float  f32x4  __attribute__((ext_vector_type(4)));

// ---------------- prep kernel: c (fused) + Yt[br,h,n] (bf16) ----------------
__global__ __launch_bounds__(256)
void rgcn_prep(const float* __restrict__ x, const float* __restrict__ rel,
               const float* __restrict__ W, __bf16* __restrict__ yt) {
    const int r = blockIdx.y, b = blockIdx.z;
    const int br = b * 10 + r;

    __shared__ float csh[64];
    if (threadIdx.x < 64) {
        const int h = threadIdx.x;
        const float* rp = rel + (size_t)br * 32;
        const float* wp = W + (size_t)h * 960 + r * 96 + 64;
        float a = 0.f;
#pragma unroll
        for (int d = 0; d < 32; ++d) a += rp[d] * wp[d];
        csh[h] = a;
    }
    __syncthreads();

    const int n = blockIdx.x * 256 + threadIdx.x;   // 0..1023
    float xr[64];
    const float* xp = x + ((size_t)b * 1024 + n) * 64;
#pragma unroll
    for (int j = 0; j < 16; ++j) {
        const float4 v = *(const float4*)(xp + j * 4);
        xr[j * 4 + 0] = v.x; xr[j * 4 + 1] = v.y;
        xr[j * 4 + 2] = v.z; xr[j * 4 + 3] = v.w;
    }

    const float* wbase = W + r * 96;                 // W[h*960 + r*96 + d]
    __bf16* yb = yt + ((size_t)br << 16) + n;        // Yt[br][h][n], br-stride 65536
    for (int h = 0; h < 64; ++h) {                   // h,d wave-uniform -> W scalar loads
        float acc = csh[h];
        const float* wr = wbase + (size_t)h * 960;
#pragma unroll
        for (int d = 0; d < 64; ++d) acc += xr[d] * wr[d];
        yb[(size_t)h << 10] = (__bf16)acc;
    }
}

// ---------------- main MFMA kernel ----------------
// FUSE=false: grid (br=160, mtile=8). All 8 mtile blocks of a (b,r) share the
//   same linear_id%8 (160%8==0) -> same XCD -> Yt slice L2-resident.
// 256 thr = 4 waves; wave owns 32m x 64h.
// A-frag: adj row (lane&15), k=(lane>>4)*8+j ; B-frag same k-map -> k-perm cancels.
// C/D: col=lane&15, row=(lane>>4)*4+reg (m89-verified).
template<bool FUSE>
__global__ __launch_bounds__(256, 4)
void rgcn_main(const float* __restrict__ adj, const __bf16* __restrict__ yt,
               float* __restrict__ partial, const float* __restrict__ bias,
               float* __restrict__ dst) {
    const int w = threadIdx.x >> 6, lane = threadIdx.x & 63;
    const int g = lane >> 4, lm = lane & 15;

#define LDNT(p, o) __builtin_nontemporal_load((const f32x4*)((p) + (o)))

    if constexpr (!FUSE) {
        const int br = blockIdx.x;             // 0..159
        const int mtile = blockIdx.y;          // 0..7
        const int mbase = mtile * 128 + w * 32;

        const float*  a0 = adj + (((size_t)br * 1024 + mbase + lm) << 10) + g * 8;
        const float*  a1 = a0 + (16 << 10);
        const __bf16* y0 = yt + ((size_t)br << 16) + (lm << 10) + g * 8;

        f32x4 acc[2][4] = {};
        f32x4 c00 = LDNT(a0, 0), c01 = LDNT(a0, 4);
        f32x4 c10 = LDNT(a1, 0), c11 = LDNT(a1, 4);

#define STEP(N0)                                                               \
        {                                                                      \
            bf16x8 av0, av1;                                                   \
            _Pragma("unroll")                                                  \
            for (int j = 0; j < 4; ++j) {                                      \
                av0[j] = (__bf16)c00[j]; av0[4 + j] = (__bf16)c01[j];          \
                av1[j] = (__bf16)c10[j]; av1[4 + j] = (__bf16)c11[j];          \
            }                                                                  \
            _Pragma("unroll")                                                  \
            for (int hf = 0; hf < 4; ++hf) {                                   \
                const bf16x8 bv = *(const bf16x8*)(y0 + hf * 16384 + (N0));    \
                acc[0][hf] = __builtin_amdgcn_mfma_f32_16x16x32_bf16(av0, bv, acc[0][hf], 0, 0, 0); \
                acc[1][hf] = __builtin_amdgcn_mfma_f32_16x16x32_bf16(av1, bv, acc[1][hf], 0, 0, 0); \
            }                                                                  \
        }

        for (int n0 = 0; n0 < 992; n0 += 32) {
            const f32x4 p00 = LDNT(a0, n0 + 32), p01 = LDNT(a0, n0 + 36);
            const f32x4 p10 = LDNT(a1, n0 + 32), p11 = LDNT(a1, n0 + 36);
            STEP(n0)
            c00 = p00; c01 = p01; c10 = p10; c11 = p11;
        }
        STEP(992)

        float* pb = partial + ((size_t)br << 16);
#pragma unroll
        for (int mf = 0; mf < 2; ++mf)
#pragma unroll
            for (int hf = 0; hf < 4; ++hf)
#pragma unroll
                for (int reg = 0; reg < 4; ++reg) {
                    const int m = mbase + mf * 16 + g * 4 + reg;
                    const int h = hf * 16 + lm;
                    pb[((size_t)m << 6) + h] = acc[mf][hf][reg];
                }
    } else {
        // fallback (small ws): grid (b=16, mtile=8), loop all 10 relations, fused epilogue
        const int b = blockIdx.x;
        const int mtile = blockIdx.y;
        const int mbase = mtile * 128 + w * 32;

        f32x4 acc[2][4] = {};
        for (int r = 0; r < 10; ++r) {
            const int br = b * 10 + r;
            const float*  a0 = adj + (((size_t)br * 1024 + mbase + lm) << 10) + g * 8;
            const float*  a1 = a0 + (16 << 10);
            const __bf16* y0 = yt + ((size_t)br << 16) + (lm << 10) + g * 8;
            f32x4 c00 = LDNT(a0, 0), c01 = LDNT(a0, 4);
            f32x4 c10 = LDNT(a1, 0), c11 = LDNT(a1, 4);
            for (int n0 = 0; n0 < 992; n0 += 32) {
                const f32x4 p00 = LDNT(a0, n0 + 32), p01 = LDNT(a0, n0 + 36);
                const f32x4 p10 = LDNT(a1, n0 + 32), p11 = LDNT(a1, n0 + 36);
                STEP(n0)
                c00 = p00; c01 = p01; c10 = p10; c11 = p11;
            }
            STEP(992)
        }
        float bvals[4];
#pragma unroll
        for (int hf = 0; hf < 4; ++hf) bvals[hf] = bias[hf * 16 + lm];
        float* db = dst + (((size_t)b * 1024 + mbase) << 6);
#pragma unroll
        for (int mf = 0; mf < 2; ++mf)
#pragma unroll
            for (int hf = 0; hf < 4; ++hf)
#pragma unroll
                for (int reg = 0; reg < 4; ++reg) {
                    const int m = mf * 16 + g * 4 + reg;
                    const int h = hf * 16 + lm;
                    db[((size_t)m << 6) + h] = fmaxf(acc[mf][hf][reg] + bvals[hf], 0.f);
                }
    }
#undef STEP
#undef LDNT
}

// ---------------- epilogue: sum 10 partial slices + bias + relu ----------------
__global__ __launch_bounds__(256)
void rgcn_epi(const float* __restrict__ partial, const float* __restrict__ bias,
              float* __restrict__ dst) {
    const size_t i = (size_t)blockIdx.x * 256 + threadIdx.x;  // f32x4 index, 262144 total
    const size_t off = i * 4;                                  // float index into [16][1024][64]
    const size_t b = off >> 16;
    const size_t inner = off & 65535;
    f32x4 s = {};
#pragma unroll
    for (int p = 0; p < 10; ++p)
        s += *(const f32x4*)(partial + (((b * 10 + p) << 16) | inner));
    const f32x4 bv = *(const f32x4*)(bias + (int)(off & 63));
#pragma unroll
    for (int j = 0; j < 4; ++j) s[j] = fmaxf(s[j] + bv[j], 0.f);
    *(f32x4*)(dst + off) = s;
}

extern "C" void kernel_launch(void* const* d_in, const int* in_sizes, int n_in,
                              void* d_out, int out_size, void* d_ws, size_t ws_size,
                              hipStream_t stream) {
    const float* x   = (const float*)d_in[0];   // [16,1024,64]
    const float* rel = (const float*)d_in[1];   // [16,10,32]
    const float* adj = (const float*)d_in[2];   // [16,10,1024,1024]
    const float* W0  = (const float*)d_in[3];   // [64,960]
    const float* b0  = (const float*)d_in[4];   // [64]
    const float* W1  = (const float*)d_in[5];
    const float* b1  = (const float*)d_in[6];
    float* out = (float*)d_out;                 // [16,1024,64]

    char* ws = (char*)d_ws;
    __bf16* Yt  = (__bf16*)ws;                  // 20,971,520 B  (160 x 64 x 1024 bf16)
    float* x2   = (float*)(ws + 20971520);      //  4,194,304 B
    float* part = (float*)(ws + 25165824);      // 41,943,040 B  (160 x 65536 f32)
    const bool big = ws_size >= 67108864;

    for (int layer = 0; layer < 2; ++layer) {
        const float* xin  = layer ? x2 : x;
        const float* W    = layer ? W1 : W0;
        const float* bias = layer ? b1 : b0;
        float* dst        = layer ? out : x2;

        rgcn_prep<<<dim3(4, 10, 16), 256, 0, stream>>>(xin, rel, W, Yt);
        if (big) {
            rgcn_main<false><<<dim3(160, 8), 256, 0, stream>>>(adj, Yt, part, nullptr, nullptr);
            rgcn_epi<<<1024, 256, 0, stream>>>(part, bias, dst);
        } else {
            rgcn_main<true><<<dim3(16, 8), 256, 0, stream>>>(adj, Yt, nullptr, bias, dst);
        }
    }
}

// Round 3
// 547.032 us; speedup vs baseline: 1.1541x; 1.1541x over previous
//
#include <hip/hip_runtime.h>
#include <hip/hip_bf16.h>

// B=16, N=1024, R=10, De=64, Dr=32, H=64, cat_in=960
// out[b,m,h] = relu( bias[h] + sum_r sum_n adj[b,r,m,n] * Yt[br,h,n] )
// Yt[br,h,n] = sum_d x[b,n,d]*W[h, r*96+d] + c[br,h]
// c[br,h]    = sum_d rel[br,d]*W[h, r*96+64+d]

typedef __bf16 bf16x8 __attribute__((ext_vector_type(8)));
typedef float  f32x4  __attribute__((ext_vector_type(4)));
typedef float  f32x8  __attribute__((ext_vector_type(8)));

// ---------------- prep kernel: c (fused) + Yt[br,h,n] (bf16, linear) ----------------
__global__ __launch_bounds__(256)
void rgcn_prep(const float* __restrict__ x, const float* __restrict__ rel,
               const float* __restrict__ W, __bf16* __restrict__ yt) {
    const int r = blockIdx.y, b = blockIdx.z;
    const int br = b * 10 + r;

    __shared__ float csh[64];
    if (threadIdx.x < 64) {
        const int h = threadIdx.x;
        const float* rp = rel + (size_t)br * 32;
        const float* wp = W + (size_t)h * 960 + r * 96 + 64;
        float a = 0.f;
#pragma unroll
        for (int d = 0; d < 32; ++d) a += rp[d] * wp[d];
        csh[h] = a;
    }
    __syncthreads();

    const int n = blockIdx.x * 256 + threadIdx.x;   // 0..1023
    float xr[64];
    const float* xp = x + ((size_t)b * 1024 + n) * 64;
#pragma unroll
    for (int j = 0; j < 16; ++j) {
        const float4 v = *(const float4*)(xp + j * 4);
        xr[j * 4 + 0] = v.x; xr[j * 4 + 1] = v.y;
        xr[j * 4 + 2] = v.z; xr[j * 4 + 3] = v.w;
    }

    const float* wbase = W + r * 96;                 // W[h*960 + r*96 + d]
    __bf16* yb = yt + ((size_t)br << 16) + n;        // Yt[br][h][n], linear
    for (int h = 0; h < 64; ++h) {                   // h,d wave-uniform -> W scalar loads
        float acc = csh[h];
        const float* wr = wbase + (size_t)h * 960;
#pragma unroll
        for (int d = 0; d < 64; ++d) acc += xr[d] * wr[d];
        yb[(size_t)h << 10] = (__bf16)acc;
    }
}

// ---------------- main kernel: Yt in LDS (swizzled), adj = only vmem stream ----------------
// grid (16*RSPAN bx, 8 mtile), 512 thr = 8 waves; wave owns 16 m x 64 h.
// bx = b*RSPAN + r0; block accumulates r = r0 + i*RSPAN, i<NRI.
// A-frag: adj row (w*16+lm), k=(lane>>4)*8+j ; B-frag same k-map (k-perm cancels).
// C/D: col=lane&15 (h), row=(lane>>4)*4+reg (m) — m89-verified, validated rounds 1-2.
// LDS swizzle: elem (h<<10) + (n ^ ((h&7)<<3))  => ds_read_b128 2-way conflict (free).
template<int NRI, bool FUSE>
__global__ __launch_bounds__(512)
void rgcn_main(const float* __restrict__ adj, const __bf16* __restrict__ yt,
               float* __restrict__ partial, const float* __restrict__ bias,
               float* __restrict__ dst) {
    constexpr int RSPAN = 10 / NRI;
    const int bx = blockIdx.x;
    const int b  = bx / RSPAN, r0 = bx % RSPAN;
    const int mtile = blockIdx.y;                   // 0..7
    const int tid = threadIdx.x;
    const int w = tid >> 6, lane = tid & 63;
    const int g = lane >> 4, lm = lane & 15;
    const int mloc = mtile * 128 + w * 16 + lm;     // adj row this lane streams
    const int msk = (lm & 7) << 3;

    __shared__ __bf16 sh[65536];                    // 128 KiB: full Yt slice

    f32x4 acc[4] = {};

    for (int i = 0; i < NRI; ++i) {
        const int r = r0 + i * RSPAN;
        const int br = b * 10 + r;

        // ---- stage Yt[br] -> LDS (swizzled), reg-staged ----
        if (i) __syncthreads();                     // previous slice fully consumed
        const __bf16* ysrc = yt + ((size_t)br << 16);
#pragma unroll
        for (int it = 0; it < 16; ++it) {
            const int e = (it * 512 + tid) * 8;     // 8-elem chunk, same h within chunk
            const uint4 v = *(const uint4*)(ysrc + e);
            const int h = e >> 10, nn = e & 1023;
            *(uint4*)(sh + (h << 10) + (nn ^ ((h & 7) << 3))) = v;
        }
        __syncthreads();

        // ---- stream adj, 4-deep pipelined (single vmem stream, counted vmcnt) ----
        const float* arow = adj + (((size_t)(br * 1024 + mloc)) << 10) + g * 8;
        f32x8 pf[4];
#pragma unroll
        for (int p = 0; p < 4; ++p)
            pf[p] = __builtin_nontemporal_load((const f32x8*)(arow + p * 32));

#pragma unroll 4
        for (int n0 = 0; n0 < 1024; n0 += 32) {
            const int slot = (n0 >> 5) & 3;         // compile-time after unroll-4
            const f32x8 cur = pf[slot];
            pf[slot] = __builtin_nontemporal_load(
                (const f32x8*)(arow + ((n0 + 128) & 1023)));  // wraps: in-bounds dummy at tail
            bf16x8 av;
#pragma unroll
            for (int j = 0; j < 8; ++j) av[j] = (__bf16)cur[j];
            const int nc = n0 + g * 8;
#pragma unroll
            for (int hf = 0; hf < 4; ++hf) {
                const int h = hf * 16 + lm;
                const bf16x8 bv = *(const bf16x8*)(sh + (h << 10) + (nc ^ msk));
                acc[hf] = __builtin_amdgcn_mfma_f32_16x16x32_bf16(av, bv, acc[hf], 0, 0, 0);
            }
        }
    }

    // ---- epilogue ----
    if (FUSE) {
        float* db = dst + (((size_t)b << 10) + mtile * 128 + w * 16) * 64;
#pragma unroll
        for (int hf = 0; hf < 4; ++hf) {
            const float bb = bias[hf * 16 + lm];
#pragma unroll
            for (int reg = 0; reg < 4; ++reg) {
                const int ml = g * 4 + reg;
                db[(size_t)ml * 64 + hf * 16 + lm] = fmaxf(acc[hf][reg] + bb, 0.f);
            }
        }
    } else {
        float* pb = partial + (((size_t)(r0 * 16 + b)) << 16)
                  + (size_t)(mtile * 128 + w * 16) * 64;
#pragma unroll
        for (int hf = 0; hf < 4; ++hf)
#pragma unroll
            for (int reg = 0; reg < 4; ++reg) {
                const int ml = g * 4 + reg;
                pb[(size_t)ml * 64 + hf * 16 + lm] = acc[hf][reg];
            }
    }
}

// ---------------- epilogue: sum NP partial slices + bias + relu ----------------
template<int NP>
__global__ __launch_bounds__(256)
void rgcn_epi(const float* __restrict__ partial, const float* __restrict__ bias,
              float* __restrict__ dst) {
    const size_t i = (size_t)blockIdx.x * 256 + threadIdx.x;  // f32x4 index, 262144 total
    const size_t off = i * 4;                                  // float idx into [16][1024][64]
    const size_t b = off >> 16;
    const size_t inner = off & 65535;
    f32x4 s = {};
#pragma unroll
    for (int p = 0; p < NP; ++p)
        s += *(const f32x4*)(partial + (((size_t)(p * 16) + b) << 16) + inner);
    const f32x4 bv = *(const f32x4*)(bias + (int)(off & 63));
#pragma unroll
    for (int j = 0; j < 4; ++j) s[j] = fmaxf(s[j] + bv[j], 0.f);
    *(f32x4*)(dst + off) = s;
}

extern "C" void kernel_launch(void* const* d_in, const int* in_sizes, int n_in,
                              void* d_out, int out_size, void* d_ws, size_t ws_size,
                              hipStream_t stream) {
    const float* x   = (const float*)d_in[0];   // [16,1024,64]
    const float* rel = (const float*)d_in[1];   // [16,10,32]
    const float* adj = (const float*)d_in[2];   // [16,10,1024,1024]
    const float* W0  = (const float*)d_in[3];   // [64,960]
    const float* b0  = (const float*)d_in[4];   // [64]
    const float* W1  = (const float*)d_in[5];
    const float* b1  = (const float*)d_in[6];
    float* out = (float*)d_out;                 // [16,1024,64]

    char* ws = (char*)d_ws;
    __bf16* Yt  = (__bf16*)ws;                  // 20,971,520 B (160 x 64 x 1024 bf16)
    float* x2   = (float*)(ws + 20971520);      //  4,194,304 B
    float* part = (float*)(ws + 25165824);      // up to 41,943,040 B
    const size_t need1 = 25165824u + 41943040u; // 67,108,864: 10 f32 slices
    const size_t need2 = 25165824u + 20971520u; // 46,137,344:  5 f32 slices

    for (int layer = 0; layer < 2; ++layer) {
        const float* xin  = layer ? x2 : x;
        const float* W    = layer ? W1 : W0;
        const float* bias = layer ? b1 : b0;
        float* dst        = layer ? out : x2;

        rgcn_prep<<<dim3(4, 10, 16), 256, 0, stream>>>(xin, rel, W, Yt);
        if (ws_size >= need1) {
            rgcn_main<1, false><<<dim3(160, 8), 512, 0, stream>>>(adj, Yt, part, nullptr, nullptr);
            rgcn_epi<10><<<1024, 256, 0, stream>>>(part, bias, dst);
        } else if (ws_size >= need2) {
            rgcn_main<2, false><<<dim3(80, 8), 512, 0, stream>>>(adj, Yt, part, nullptr, nullptr);
            rgcn_epi<5><<<1024, 256, 0, stream>>>(part, bias, dst);
        } else {
            rgcn_main<10, true><<<dim3(16, 8), 512, 0, stream>>>(adj, Yt, nullptr, bias, dst);
        }
    }
}